// Round 8
// baseline (131.357 us; speedup 1.0000x reference)
//
#include <hip/hip_runtime.h>

typedef float f32x16 __attribute__((ext_vector_type(16)));
typedef float f32x2 __attribute__((ext_vector_type(2)));
typedef short short8 __attribute__((ext_vector_type(8)));
typedef unsigned short u16;
typedef unsigned int u32;

#define SEQ_L 2048

#if __has_builtin(__builtin_amdgcn_exp2f)
#define EXP2(x) __builtin_amdgcn_exp2f(x)
#else
#define EXP2(x) exp2f(x)
#endif

__device__ __forceinline__ u32 pk2bf(float lo, float hi) {
#if __has_builtin(__builtin_amdgcn_cvt_pk_bf16_f32)
    typedef __bf16 bf16x2_t __attribute__((ext_vector_type(2)));
    union { bf16x2_t v; u32 i; } w;
    w.v = __builtin_amdgcn_cvt_pk_bf16_f32(lo, hi);
    return w.i;
#else
    union { float f; u32 i; } a, b; a.f = lo; b.f = hi;
    return ((a.i + 0x8000u) >> 16) | ((b.i + 0x8000u) & 0xFFFF0000u);
#endif
}

// async global->LDS, 16 B per lane; LDS dest = wave-uniform base + lane*16.
__device__ __forceinline__ void gl16(const void* g, void* l) {
    __builtin_amdgcn_global_load_lds(
        (const __attribute__((address_space(1))) unsigned int*)g,
        (__attribute__((address_space(3))) unsigned int*)l, 16, 0, 0);
}

// Workspace tile layout (per head h, per 64-s tile T): 16384 B
//   [0..8191]    kt: XOR-swizzled [s][c] bf16 (exact LDS byte order, proven layout)
//   [8192..16383] vt: s-permuted [c][s'] bf16, stride 64 u16, XOR ((c&7)<<3)
#define KT_U16 4096
#define VT_U16 4096
#define GRP_U16 8192                  // one group tile (K+V) = 16 KB
#define BUF_U16 16384                 // both groups, one slot = 32 KB
#define SMEM_U16 32768                // double buffer = 64 KB; epilogue 33792 B fits

// ---------------- pre-pass: fp32 -> bf16 repack into swizzled tiles ----------------
__global__ __launch_bounds__(256)
void prepack_kernel(const float* __restrict__ qkv, u16* __restrict__ ws) {
    const int tid = threadIdx.x;
    const int bid = blockIdx.x;       // 32 heads x 32 tiles = 1024
    const int h = bid & 31, T = bid >> 5;
    const int bb = h >> 3, hh = h & 7;
    const float* kp = qkv + ((size_t)bb * 1536 + (size_t)hh * 64 + 512) * SEQ_L;
    const float* vp = qkv + ((size_t)bb * 1536 + (size_t)hh * 64 + 1024) * SEQ_L;
    const int sgrp = tid & 15;        // s-chunk: 4*sgrp..+3
    const int rq   = tid >> 4;        // K rows 4rq..4rq+3 / V rows rq+16rr
    const int sb   = T * 64;

    u16* wsK = ws + (size_t)(h * 32 + T) * GRP_U16;
    u16* wsV = wsK + KT_U16;

    float4 kreg[4], vreg[4];
#pragma unroll
    for (int rr = 0; rr < 4; ++rr) {
        kreg[rr] = *(const float4*)(kp + (size_t)(4 * rq + rr) * SEQ_L + sb + 4 * sgrp);
        vreg[rr] = *(const float4*)(vp + (size_t)(rq + 16 * rr) * SEQ_L + sb + 4 * sgrp);
    }
    // kt writes (identical formula to the proven in-kernel publish)
#pragma unroll
    for (int j = 0; j < 4; ++j) {
        int s = 4 * sgrp + j;
        int sw = ((s >> 2) ^ s) & 7;
        u16* kw = wsK + s * 64 + (((rq >> 1) ^ sw) << 3) + ((rq & 1) << 2);
        uint2 w;
        w.x = pk2bf(kreg[0][j], kreg[1][j]);
        w.y = pk2bf(kreg[2][j], kreg[3][j]);
        *(uint2*)kw = w;
    }
    // vt writes: same s-permutation positions, stride 64 + XOR ((c&7)<<3)
    const int vcol = ((sgrp >> 2) << 4) + ((sgrp & 1) << 3) + (((sgrp >> 1) & 1) << 2);
    const int vx = vcol ^ ((rq & 7) << 3);   // (c&7)==(rq&7) for all rr
#pragma unroll
    for (int rr = 0; rr < 4; ++rr) {
        int c = rq + 16 * rr;
        uint2 w;
        w.x = pk2bf(vreg[rr].x, vreg[rr].y);
        w.y = pk2bf(vreg[rr].z, vreg[rr].w);
        *(uint2*)(wsV + c * 64 + vx) = w;
    }
}

// ---------------- main kernel ----------------
// WG = 512 thr = 8 waves = 2 s-groups x 4 t-waves; each wave owns ONE 32-t
// tile -> WG covers 128 t. Grid = 32 heads x 16 tb = 512 WGs = 2 WGs/CU =
// 4 waves/SIMD (LDS 64 KB x2 = 128 KB/CU; regs engineered <= 128: staging
// regs/publish VALU removed — staging is 4x global_load_lds per thread).
__global__ __launch_bounds__(512, 4)
void attn_kernel(const float* __restrict__ qkv, const u16* __restrict__ ws,
                 float* __restrict__ out) {
    const int tid  = threadIdx.x;
    const int lane = tid & 63;
    const int wv   = tid >> 6;        // 0..7
    const int g    = wv >> 2;         // s-group 0/1
    const int wvin = wv & 3;          // t-wave within group
    const int col  = lane & 31;
    const int half = lane >> 5;

    const int gid  = blockIdx.x;      // 0..511
    const int head = gid & 31;        // all tb-WGs of a head share an XCD L2
    const int tb   = gid >> 5;        // 0..15
    const int t0   = tb * 128 + wvin * 32;
    const int bb   = head >> 3, hh = head & 7;

    const size_t qoff = ((size_t)bb * 1536 + (size_t)hh * 64) * SEQ_L;
    const float* qp = qkv + qoff;
    float* op = out + ((size_t)bb * 512 + (size_t)hh * 64) * SEQ_L;

    __shared__ __align__(16) u16 smem[SMEM_U16];
    u16* ktg = smem + g * GRP_U16;    // buffer-0 base; buffer 1 = +BUF_U16
    u16* vtg = ktg + KT_U16;

    // ---- LDS read offsets (proven kt; vt stride-64 + XOR) ----
    const int sw_r = ((col >> 2) ^ col) & 7;
    int kco[4];
#pragma unroll
    for (int ks = 0; ks < 4; ++ks) kco[ks] = ((2 * ks + half) ^ sw_r) << 3;
    int vco[4];
#pragma unroll
    for (int mk = 0; mk < 4; ++mk) vco[mk] = (half * 8 + mk * 16) ^ ((col & 7) << 3);
    const u16* krb0 = ktg + col * 64;
    const u16* krb1 = ktg + (32 + col) * 64;
    const u16* vrb0 = vtg + col * 64;
    const u16* vrb1 = vtg + (32 + col) * 64;

    // ---- staging pointers: per-lane global src, uniform LDS dest ----
    const char* ws_lane = (const char*)ws
        + ((size_t)(head * 32 + g * 16) << 14) + wvin * 2048 + lane * 16;
    const int lgrp = __builtin_amdgcn_readfirstlane(g * 16384 + wvin * 2048);
    char* ldsb = (char*)smem;

    // ---- preload Q B-fragment (prescaled) ----
    const int tA = t0 + col;
    const float qscale = 0.18033688f;  // (1/8)*log2(e)
    short8 qfA[4];
#pragma unroll
    for (int ks = 0; ks < 4; ++ks) {
        union { u32 u[4]; short8 v; } qa;
#pragma unroll
        for (int e2 = 0; e2 < 4; ++e2) {
            int c = ks * 16 + half * 8 + 2 * e2;
            const float* c0 = qp + (size_t)c * SEQ_L;
            const float* c1 = qp + (size_t)(c + 1) * SEQ_L;
            qa.u[e2] = pk2bf(c0[tA] * qscale, c1[tA] * qscale);
        }
        qfA[ks] = qa.v;
    }

    f32x16 zacc;
#pragma unroll
    for (int r = 0; r < 16; ++r) zacc[r] = 0.0f;
    f32x16 accO[2];
#pragma unroll
    for (int m = 0; m < 2; ++m)
#pragma unroll
        for (int r = 0; r < 16; ++r) accO[m][r] = 0.0f;
    f32x2 lsA = {0.0f, 0.0f};

    // 4 async loads stage one 16-KB group tile (K 8KB + V 8KB; this wave's 4KB)
    auto STAGE = [&](const char* p, int bufbyte) {
        gl16(p,        ldsb + bufbyte + lgrp);
        gl16(p + 1024, ldsb + bufbyte + lgrp + 1024);
        gl16(p + 8192, ldsb + bufbyte + lgrp + 8192);
        gl16(p + 9216, ldsb + bufbyte + lgrp + 9216);
    };

    // ---- prologue: stage tile 0 ----
    STAGE(ws_lane, 0);
    const char* stp = ws_lane + 16384;
    __syncthreads();

#pragma unroll 2
    for (int it = 0; it < 16; ++it) {
        const int bo_c  = (it & 1) * BUF_U16;            // u16 units
        const int bufn  = ((it + 1) & 1) * (BUF_U16 * 2); // bytes
        // ---- issue next tile's async stage (lands under this compute) ----
        if (it + 1 < 16) STAGE(stp, bufn);
        stp += 16384;

        // ---- S^T = K^T * Q (8 MFMAs) ----
        f32x16 accA[2];
        __builtin_amdgcn_s_setprio(1);
#pragma unroll
        for (int mb = 0; mb < 2; ++mb) {
            const u16* rb = (mb ? krb1 : krb0) + bo_c;
            short8 kf0 = *(const short8*)(rb + kco[0]);
            accA[mb] = __builtin_amdgcn_mfma_f32_32x32x16_bf16(kf0, qfA[0], zacc, 0, 0, 0);
#pragma unroll
            for (int ks = 1; ks < 4; ++ks) {
                short8 kf = *(const short8*)(rb + kco[ks]);
                accA[mb] = __builtin_amdgcn_mfma_f32_32x32x16_bf16(kf, qfA[ks], accA[mb], 0, 0, 0);
            }
        }
        __builtin_amdgcn_s_setprio(0);

        // ---- per mb-half: exp2+pack then PV (preg stays at 8 regs) ----
#pragma unroll
        for (int mb = 0; mb < 2; ++mb) {
            u32 preg[8];
            f32x2 a2[4];
#pragma unroll
            for (int u2 = 0; u2 < 8; ++u2) {
                float ax = EXP2(accA[mb][2 * u2]);
                float ay = EXP2(accA[mb][2 * u2 + 1]);
                preg[u2] = pk2bf(ax, ay);
                f32x2 av = {ax, ay};
                if (u2 < 4) a2[u2] = av; else a2[u2 - 4] += av;
            }
            lsA += (a2[0] + a2[1]) + (a2[2] + a2[3]);

            __builtin_amdgcn_s_setprio(1);
#pragma unroll
            for (int kb = 0; kb < 2; ++kb) {
                int mk = 2 * mb + kb;
                union { u32 u[4]; short8 v; } bf;
#pragma unroll
                for (int i = 0; i < 4; ++i) bf.u[i] = preg[4 * kb + i];
#pragma unroll
                for (int mbc = 0; mbc < 2; ++mbc) {
                    short8 vf = *(const short8*)((mbc ? vrb1 : vrb0) + bo_c + vco[mk]);
                    accO[mbc] = __builtin_amdgcn_mfma_f32_32x32x16_bf16(vf, bf.v, accO[mbc], 0, 0, 0);
                }
            }
            __builtin_amdgcn_s_setprio(0);
        }

        __syncthreads();   // stage landed (vmcnt 0) + all reads of cur done
    }

    float lsum = lsA[0] + lsA[1];

    // ---- combine the two s-groups, then store ----
    float* ep = (float*)smem;           // 256 rows x 33 floats = 33792 B
    if (g == 1) {
        float* row = ep + (wvin * 64 + lane) * 33;
#pragma unroll
        for (int mbc = 0; mbc < 2; ++mbc)
#pragma unroll
            for (int r = 0; r < 16; ++r) row[mbc * 16 + r] = accO[mbc][r];
        row[32] = lsum;
    }
    __syncthreads();
    if (g == 0) {
        const float* row = ep + (wvin * 64 + lane) * 33;
#pragma unroll
        for (int mbc = 0; mbc < 2; ++mbc)
#pragma unroll
            for (int r = 0; r < 16; ++r) accO[mbc][r] += row[mbc * 16 + r];
        float lt = lsum + row[32];
        float ltot = lt + __shfl_xor(lt, 32, 64);
        float inv = 1.0f / ltot;
#pragma unroll
        for (int mbc = 0; mbc < 2; ++mbc) {
#pragma unroll
            for (int r = 0; r < 16; ++r) {
                int c = mbc * 32 + (r & 3) + 8 * (r >> 2) + 4 * half;
                op[(size_t)c * SEQ_L + tA] = accO[mbc][r] * inv;
            }
        }
    }
}

extern "C" void kernel_launch(void* const* d_in, const int* in_sizes, int n_in,
                              void* d_out, int out_size, void* d_ws, size_t ws_size,
                              hipStream_t stream) {
    (void)in_sizes; (void)n_in; (void)ws_size; (void)out_size;
    const float* qkv = (const float*)d_in[0];
    float* out = (float*)d_out;
    u16* ws = (u16*)d_ws;               // needs 16 MB: 32 heads x 32 tiles x 16 KB
    prepack_kernel<<<dim3(1024), dim3(256), 0, stream>>>(qkv, ws);
    attn_kernel<<<dim3(512), dim3(512), 0, stream>>>(qkv, ws, out);
}